// Round 2
// baseline (1168.675 us; speedup 1.0000x reference)
//
#include <hip/hip_runtime.h>

#define S_LEN 2048
#define DMODEL 256
#define DINNER 512
#define NCHUNK 64
#define CLEN 32

typedef unsigned short u16;

__device__ __forceinline__ float bf2f(u16 u) {
  unsigned int x = ((unsigned int)u) << 16;
  float f; __builtin_memcpy(&f, &x, 4); return f;
}
__device__ __forceinline__ u16 f2bf(float f) {
  unsigned int x; __builtin_memcpy(&x, &f, 4);
  return (u16)((x + 0x7FFFu + ((x >> 16) & 1u)) >> 16);
}
__device__ __forceinline__ float ldw(const void* p, size_t i, int isbf) {
  return isbf ? bf2f(((const u16*)p)[i]) : ((const float*)p)[i];
}
__device__ __forceinline__ float siluf(float x) { return x / (1.f + __expf(-x)); }
__device__ __forceinline__ float softplusf(float x) {
  if (x > 20.f) return x;
  return log1pf(__expf(x));
}

// Detect input dtype: even-indexed u16s of an f32 array are mantissa
// low-halves (near-uniform exponent byte); of a bf16 ~N(0,1) array they are
// valid bf16s with exponent in [0x60,0x8F] w.p. ~1.
__global__ __launch_bounds__(256) void detect_kernel(const void* __restrict__ x,
                                                     int* __restrict__ flag) {
  __shared__ int cnt;
  if (threadIdx.x == 0) cnt = 0;
  __syncthreads();
  u16 u = ((const u16*)x)[2 * threadIdx.x];
  int e = (u >> 7) & 0xFF;
  if (e >= 0x60 && e <= 0x8F) atomicAdd(&cnt, 1);
  __syncthreads();
  if (threadIdx.x == 0) *flag = (cnt > 128) ? 1 : 0;
}

__global__ __launch_bounds__(256) void ln_kernel(
    const void* __restrict__ src, int src_is_ext, int rev,
    const void* __restrict__ g, const void* __restrict__ bta, size_t wo,
    const int* __restrict__ pf, float* __restrict__ res, float* __restrict__ xn)
{
  const int isbf = *pf;
  int r = blockIdx.x;
  int tid = threadIdx.x;
  int b = r >> 11, s = r & 2047;
  int sr = rev ? (b * S_LEN + (S_LEN - 1 - s)) : r;
  float v;
  if (src_is_ext) v = ldw(src, (size_t)sr * DMODEL + tid, isbf);
  else            v = ((const float*)src)[(size_t)sr * DMODEL + tid];
  res[(size_t)r * DMODEL + tid] = v;
  float s1 = v, s2 = v * v;
#pragma unroll
  for (int o = 32; o > 0; o >>= 1) {
    s1 += __shfl_xor(s1, o, 64);
    s2 += __shfl_xor(s2, o, 64);
  }
  __shared__ float r1[4], r2[4];
  if ((tid & 63) == 0) { r1[tid >> 6] = s1; r2[tid >> 6] = s2; }
  __syncthreads();
  s1 = r1[0] + r1[1] + r1[2] + r1[3];
  s2 = r2[0] + r2[1] + r2[2] + r2[3];
  float mean = s1 * (1.f / DMODEL);
  float var  = s2 * (1.f / DMODEL) - mean * mean;
  float inv  = rsqrtf(var + 1e-5f);
  xn[(size_t)r * DMODEL + tid] = (v - mean) * inv * ldw(g, wo + tid, isbf) + ldw(bta, wo + tid, isbf);
}

// C[M,N] = A[M,K](f32) @ W[K,N] [+ res]; OUTMODE 0: f32 ws, 1: final out per flag.
template<int OUTMODE>
__global__ __launch_bounds__(256) void gemm_kernel(
    const float* __restrict__ A, const void* __restrict__ W, size_t wo,
    const float* __restrict__ res, void* __restrict__ Out,
    const int* __restrict__ pf, int N, int K)
{
  const int isbf = *pf;
  __shared__ float As[64 * 17];
  __shared__ float Ws[16 * 64];
  int tid = threadIdx.x;
  int m0 = blockIdx.y << 6, n0 = blockIdx.x << 6;
  int tx = tid & 15, ty = tid >> 4;
  int lam = tid >> 2, lak = (tid & 3) << 2;
  int lwk = tid >> 4, lwn = (tid & 15) << 2;
  float acc[4][4] = {};
  for (int k0 = 0; k0 < K; k0 += 16) {
    float4 av = *(const float4*)(A + (size_t)(m0 + lam) * K + k0 + lak);
    As[lam * 17 + lak + 0] = av.x;
    As[lam * 17 + lak + 1] = av.y;
    As[lam * 17 + lak + 2] = av.z;
    As[lam * 17 + lak + 3] = av.w;
    size_t woff = wo + (size_t)(k0 + lwk) * N + n0 + lwn;
    if (isbf) {
      ushort4 wv = *(const ushort4*)((const u16*)W + woff);
      Ws[lwk * 64 + lwn + 0] = bf2f(wv.x);
      Ws[lwk * 64 + lwn + 1] = bf2f(wv.y);
      Ws[lwk * 64 + lwn + 2] = bf2f(wv.z);
      Ws[lwk * 64 + lwn + 3] = bf2f(wv.w);
    } else {
      float4 wv = *(const float4*)((const float*)W + woff);
      Ws[lwk * 64 + lwn + 0] = wv.x;
      Ws[lwk * 64 + lwn + 1] = wv.y;
      Ws[lwk * 64 + lwn + 2] = wv.z;
      Ws[lwk * 64 + lwn + 3] = wv.w;
    }
    __syncthreads();
#pragma unroll
    for (int kk = 0; kk < 16; ++kk) {
      float a0 = As[(ty * 4 + 0) * 17 + kk];
      float a1 = As[(ty * 4 + 1) * 17 + kk];
      float a2 = As[(ty * 4 + 2) * 17 + kk];
      float a3 = As[(ty * 4 + 3) * 17 + kk];
      float4 w4 = *(const float4*)(Ws + kk * 64 + (tx << 2));
      acc[0][0] += a0 * w4.x; acc[0][1] += a0 * w4.y; acc[0][2] += a0 * w4.z; acc[0][3] += a0 * w4.w;
      acc[1][0] += a1 * w4.x; acc[1][1] += a1 * w4.y; acc[1][2] += a1 * w4.z; acc[1][3] += a1 * w4.w;
      acc[2][0] += a2 * w4.x; acc[2][1] += a2 * w4.y; acc[2][2] += a2 * w4.z; acc[2][3] += a2 * w4.w;
      acc[3][0] += a3 * w4.x; acc[3][1] += a3 * w4.y; acc[3][2] += a3 * w4.z; acc[3][3] += a3 * w4.w;
    }
    __syncthreads();
  }
#pragma unroll
  for (int i = 0; i < 4; ++i) {
    int row = m0 + ty * 4 + i;
#pragma unroll
    for (int j = 0; j < 4; ++j) {
      int col = n0 + (tx << 2) + j;
      float v = acc[i][j];
      if (res) v += res[(size_t)row * N + col];
      size_t oidx = (size_t)row * N + col;
      if (OUTMODE == 0) ((float*)Out)[oidx] = v;
      else { if (isbf) ((u16*)Out)[oidx] = f2bf(v); else ((float*)Out)[oidx] = v; }
    }
  }
}

__global__ __launch_bounds__(256) void conv_kernel(
    const float* __restrict__ xz, const void* __restrict__ cw, const void* __restrict__ cb,
    size_t ow, size_t ob, const int* __restrict__ pf, float* __restrict__ xc)
{
  const int isbf = *pf;
  int idx = blockIdx.x * 256 + threadIdx.x;  // 4096*512
  int r = idx >> 9, d = idx & 511;
  int b = r >> 11, s = r & 2047;
  float acc = ldw(cb, ob + d, isbf);
#pragma unroll
  for (int k = 0; k < 4; ++k) {
    int t = s - 3 + k;
    if (t >= 0) acc += ldw(cw, ow + (size_t)d * 4 + k, isbf) * xz[((size_t)(b * S_LEN + t) << 10) + d];
  }
  xc[idx] = siluf(acc);
}

__global__ __launch_bounds__(256) void skinny1_kernel(
    const float* __restrict__ xc, const void* __restrict__ xdw,
    const void* __restrict__ xBw, const void* __restrict__ xCw,
    size_t od, size_t oB, size_t oC, const int* __restrict__ pf,
    float* __restrict__ dtmp, float* __restrict__ Bm, float* __restrict__ Cm)
{
  const int isbf = *pf;
  __shared__ float xs[512];
  __shared__ float part[4][64];
  int r = blockIdx.x, tid = threadIdx.x;
  xs[tid]       = xc[(size_t)r * 512 + tid];
  xs[tid + 256] = xc[(size_t)r * 512 + tid + 256];
  __syncthreads();
  int o = tid & 63, q = tid >> 6;
  int kbeg = q * 128;
  float s = 0.f;
  if (o < 32) {
    for (int kk = 0; kk < 128; ++kk) { int k = kbeg + kk; s += xs[k] * ldw(xdw, od + (size_t)k * 32 + o, isbf); }
  } else if (o < 48) {
    int oo = o - 32;
    for (int kk = 0; kk < 128; ++kk) { int k = kbeg + kk; s += xs[k] * ldw(xBw, oB + (size_t)k * 16 + oo, isbf); }
  } else {
    int oo = o - 48;
    for (int kk = 0; kk < 128; ++kk) { int k = kbeg + kk; s += xs[k] * ldw(xCw, oC + (size_t)k * 16 + oo, isbf); }
  }
  part[q][o] = s;
  __syncthreads();
  if (tid < 64) {
    float v = part[0][tid] + part[1][tid] + part[2][tid] + part[3][tid];
    if (tid < 32)      dtmp[(size_t)r * 32 + tid] = v;
    else if (tid < 48) Bm[(size_t)r * 16 + (tid - 32)] = v;
    else               Cm[(size_t)r * 16 + (tid - 48)] = v;
  }
}

__global__ __launch_bounds__(256) void skinny2_kernel(
    const float* __restrict__ dtmp, const void* __restrict__ dtpw, const void* __restrict__ dtpb,
    size_t ow, size_t ob, const int* __restrict__ pf, float* __restrict__ delta)
{
  const int isbf = *pf;
  int idx = blockIdx.x * 256 + threadIdx.x;
  int r = idx >> 9, d = idx & 511;
  float s = ldw(dtpb, ob + d, isbf);
#pragma unroll 8
  for (int j = 0; j < 32; ++j) s += dtmp[(size_t)r * 32 + j] * ldw(dtpw, ow + (size_t)j * 512 + d, isbf);
  delta[idx] = softplusf(s);
}

__global__ __launch_bounds__(256) void scan_chunk_kernel(
    const float* __restrict__ delta, const float* __restrict__ xc, const float* __restrict__ Bm,
    const void* __restrict__ A_log, size_t oA, const int* __restrict__ pf,
    float* __restrict__ aggA, float* __restrict__ aggB)
{
  const int isbf = *pf;
  int tid = threadIdx.x;
  int n = tid & 15, dl = tid >> 4;
  int d = (blockIdx.x << 4) + dl;
  int c = blockIdx.y, b = blockIdx.z;
  float Ac = -__expf(ldw(A_log, oA + (size_t)d * 16 + n, isbf));
  float h = 0.f, lacc = 0.f;
  int row0 = b * S_LEN + c * CLEN;
  for (int tt = 0; tt < CLEN; ++tt) {
    int row = row0 + tt;
    float de = delta[(size_t)row * DINNER + d];
    float xv = xc[(size_t)row * DINNER + d];
    float bv = Bm[(size_t)row * 16 + n];
    float u = de * Ac;
    h = __expf(u) * h + de * xv * bv;
    lacc += u;
  }
  size_t o = (((size_t)(b * NCHUNK + c) * DINNER) + d) * 16 + n;
  aggA[o] = __expf(lacc);
  aggB[o] = h;
}

// exclusive prefix over chunks, in place: aggB becomes hpref.
__global__ __launch_bounds__(256) void scan_prefix_kernel(
    const float* __restrict__ aggA, float* __restrict__ aggB)
{
  int idx = blockIdx.x * 256 + threadIdx.x;  // 2*512*16
  int n = idx & 15, d = (idx >> 4) & 511, b = idx >> 13;
  float h = 0.f;
  for (int c = 0; c < NCHUNK; ++c) {
    size_t o = (((size_t)(b * NCHUNK + c) * DINNER) + d) * 16 + n;
    float a = aggA[o], t = aggB[o];
    aggB[o] = h;
    h = a * h + t;
  }
}

__global__ __launch_bounds__(256) void scan_apply_kernel(
    const float* __restrict__ delta, const float* __restrict__ xc, const float* __restrict__ Bm,
    const float* __restrict__ Cm, const float* __restrict__ xz, const float* __restrict__ hpref,
    const void* __restrict__ A_log, size_t oA, const void* __restrict__ Dp, size_t oD,
    const int* __restrict__ pf, float* __restrict__ ym)
{
  const int isbf = *pf;
  int tid = threadIdx.x;
  int n = tid & 15, dl = tid >> 4;
  int d = (blockIdx.x << 4) + dl;
  int c = blockIdx.y, b = blockIdx.z;
  float Ac = -__expf(ldw(A_log, oA + (size_t)d * 16 + n, isbf));
  size_t o = (((size_t)(b * NCHUNK + c) * DINNER) + d) * 16 + n;
  float h = hpref[o];
  float Dv = ldw(Dp, oD + d, isbf);
  int row0 = b * S_LEN + c * CLEN;
  for (int tt = 0; tt < CLEN; ++tt) {
    int row = row0 + tt;
    float de = delta[(size_t)row * DINNER + d];
    float xv = xc[(size_t)row * DINNER + d];
    float bv = Bm[(size_t)row * 16 + n];
    float cv = Cm[(size_t)row * 16 + n];
    h = __expf(de * Ac) * h + de * xv * bv;
    float yc = h * cv;
    yc += __shfl_xor(yc, 1, 64);
    yc += __shfl_xor(yc, 2, 64);
    yc += __shfl_xor(yc, 4, 64);
    yc += __shfl_xor(yc, 8, 64);
    if (n == 0) {
      float zv = xz[((size_t)row << 10) + 512 + d];
      float y = yc + Dv * xv;
      ym[(size_t)row * DINNER + d] = y * siluf(zv);
    }
  }
}

__global__ __launch_bounds__(256) void cat_kernel(
    const float* __restrict__ ofwd, const float* __restrict__ obwd, float* __restrict__ cat)
{
  int idx = blockIdx.x * 256 + threadIdx.x;
  int r = idx >> 9, ccol = idx & 511;
  int b = r >> 11, s = r & 2047;
  float v;
  if (ccol < 256) v = ofwd[(size_t)r * 256 + ccol];
  else v = obwd[(size_t)(b * S_LEN + (S_LEN - 1 - s)) * 256 + (ccol - 256)];
  cat[idx] = v;
}

extern "C" void kernel_launch(void* const* d_in, const int* in_sizes, int n_in,
                              void* d_out, int out_size, void* d_ws, size_t ws_size,
                              hipStream_t stream)
{
  const void* x       = d_in[0];
  const void* in_w    = d_in[1];
  const void* conv_w  = d_in[2];
  const void* conv_b  = d_in[3];
  const void* A_log   = d_in[4];
  const void* xd_w    = d_in[5];
  const void* xB_w    = d_in[6];
  const void* xC_w    = d_in[7];
  const void* dtp_w   = d_in[8];
  const void* dtp_b   = d_in[9];
  const void* Dp      = d_in[10];
  const void* out_w   = d_in[11];
  const void* ln_g    = d_in[12];
  const void* ln_b    = d_in[13];
  const void* merge_w = d_in[14];

  const size_t M = 4096;
  float* ws = (float*)d_ws;
  float* res   = ws;                          // 1M floats
  float* dxn   = res + M * 256;               // 2M region: xn then delta (disjoint lifetimes)
  float* xn    = dxn;
  float* delta = dxn;
  float* xz    = dxn + M * 512;               // 4M
  float* xc    = xz + M * 1024;               // 2M
  float* dtmp  = xc + M * 512;                // 128K
  float* Bm    = dtmp + M * 32;               // 64K
  float* Cm    = Bm + M * 16;                 // 64K
  float* aggA  = Cm + M * 16;                 // 1M
  float* aggB  = aggA + (size_t)2 * NCHUNK * DINNER * 16;  // 1M (becomes hpref)
  float* ymb   = aggB + (size_t)2 * NCHUNK * DINNER * 16;  // 2M
  float* obA   = ymb + M * 512;               // 1M (blocks 0 and 2)
  float* ob1   = obA + M * 256;               // 1M
  float* ob3   = ob1 + M * 256;               // 1M
  int*   flagp = (int*)(ob3 + M * 256);
  float* catb  = xz;                          // xz free by merge time

  dim3 blk(256);
  hipLaunchKernelGGL(detect_kernel, dim3(1), blk, 0, stream, x, flagp);

  for (int i = 0; i < 4; ++i) {
    const void* src; int ext, rev; float* dst;
    if (i == 0)      { src = x;   ext = 1; rev = 0; dst = obA; }
    else if (i == 1) { src = obA; ext = 0; rev = 0; dst = ob1; }
    else if (i == 2) { src = x;   ext = 1; rev = 1; dst = obA; }
    else             { src = obA; ext = 0; rev = 0; dst = ob3; }

    hipLaunchKernelGGL(ln_kernel, dim3(4096), blk, 0, stream,
        src, ext, rev, ln_g, ln_b, (size_t)i * 256, flagp, res, xn);
    hipLaunchKernelGGL((gemm_kernel<0>), dim3(16, 64), blk, 0, stream,
        xn, in_w, (size_t)i * 256 * 1024, (const float*)nullptr, (void*)xz, flagp, 1024, 256);
    hipLaunchKernelGGL(conv_kernel, dim3(8192), blk, 0, stream,
        xz, conv_w, conv_b, (size_t)i * 512 * 4, (size_t)i * 512, flagp, xc);
    hipLaunchKernelGGL(skinny1_kernel, dim3(4096), blk, 0, stream,
        xc, xd_w, xB_w, xC_w, (size_t)i * 512 * 32, (size_t)i * 512 * 16, (size_t)i * 512 * 16,
        flagp, dtmp, Bm, Cm);
    hipLaunchKernelGGL(skinny2_kernel, dim3(8192), blk, 0, stream,
        dtmp, dtp_w, dtp_b, (size_t)i * 32 * 512, (size_t)i * 512, flagp, delta);
    hipLaunchKernelGGL(scan_chunk_kernel, dim3(32, 64, 2), blk, 0, stream,
        delta, xc, Bm, A_log, (size_t)i * 512 * 16, flagp, aggA, aggB);
    hipLaunchKernelGGL(scan_prefix_kernel, dim3(64), blk, 0, stream, aggA, aggB);
    hipLaunchKernelGGL(scan_apply_kernel, dim3(32, 64, 2), blk, 0, stream,
        delta, xc, Bm, Cm, xz, aggB, A_log, (size_t)i * 512 * 16, Dp, (size_t)i * 512,
        flagp, ymb);
    hipLaunchKernelGGL((gemm_kernel<0>), dim3(4, 64), blk, 0, stream,
        ymb, out_w, (size_t)i * 512 * 256, res, (void*)dst, flagp, 256, 512);
  }
  hipLaunchKernelGGL(cat_kernel, dim3(8192), blk, 0, stream, ob1, ob3, catb);
  hipLaunchKernelGGL((gemm_kernel<1>), dim3(4, 64), blk, 0, stream,
      catb, merge_w, (size_t)0, (const float*)nullptr, d_out, flagp, 256, 512);
}

// Round 3
// 949.650 us; speedup vs baseline: 1.2306x; 1.2306x over previous
//
#include <hip/hip_runtime.h>

#define S_LEN 2048
#define DMODEL 256
#define DINNER 512
#define NCHUNK 64
#define CLEN 32

typedef unsigned short u16;

__device__ __forceinline__ float bf2f(u16 u) {
  unsigned int x = ((unsigned int)u) << 16;
  float f; __builtin_memcpy(&f, &x, 4); return f;
}
__device__ __forceinline__ u16 f2bf(float f) {
  unsigned int x; __builtin_memcpy(&x, &f, 4);
  return (u16)((x + 0x7FFFu + ((x >> 16) & 1u)) >> 16);
}
__device__ __forceinline__ float ldw(const void* p, size_t i, int isbf) {
  return isbf ? bf2f(((const u16*)p)[i]) : ((const float*)p)[i];
}
__device__ __forceinline__ float siluf(float x) { return x / (1.f + __expf(-x)); }
__device__ __forceinline__ float softplusf(float x) {
  if (x > 20.f) return x;
  return log1pf(__expf(x));
}

// Detect input dtype: even-indexed u16s of an f32 array are mantissa
// low-halves (near-uniform exponent byte); of a bf16 ~N(0,1) array they are
// valid bf16s with exponent in [0x60,0x8F] w.p. ~1.
__global__ __launch_bounds__(256) void detect_kernel(const void* __restrict__ x,
                                                     int* __restrict__ flag) {
  __shared__ int cnt;
  if (threadIdx.x == 0) cnt = 0;
  __syncthreads();
  u16 u = ((const u16*)x)[2 * threadIdx.x];
  int e = (u >> 7) & 0xFF;
  if (e >= 0x60 && e <= 0x8F) atomicAdd(&cnt, 1);
  __syncthreads();
  if (threadIdx.x == 0) *flag = (cnt > 128) ? 1 : 0;
}

// Pack xd_w|xB_w|xC_w into fused f32 weight Wall[NB][512][64].
__global__ __launch_bounds__(256) void pack_kernel(
    const void* __restrict__ xdw, const void* __restrict__ xBw, const void* __restrict__ xCw,
    const int* __restrict__ pf, float* __restrict__ Wall)
{
  const int isbf = *pf;
  int idx = blockIdx.x * 256 + threadIdx.x;   // 4*512*64 = 131072
  int j = idx & 63, r = (idx >> 6) & 511, i = idx >> 15;
  float v;
  if (j < 32)      v = ldw(xdw, (size_t)i * 16384 + (size_t)r * 32 + j, isbf);
  else if (j < 48) v = ldw(xBw, (size_t)i * 8192 + (size_t)r * 16 + (j - 32), isbf);
  else             v = ldw(xCw, (size_t)i * 8192 + (size_t)r * 16 + (j - 48), isbf);
  Wall[idx] = v;
}

__global__ __launch_bounds__(256) void ln_kernel(
    const void* __restrict__ src, int src_is_ext, int rev,
    const void* __restrict__ g, const void* __restrict__ bta, size_t wo,
    const int* __restrict__ pf, float* __restrict__ res, float* __restrict__ xn)
{
  const int isbf = *pf;
  int r = blockIdx.x;
  int tid = threadIdx.x;
  int b = r >> 11, s = r & 2047;
  int sr = rev ? (b * S_LEN + (S_LEN - 1 - s)) : r;
  float v;
  if (src_is_ext) v = ldw(src, (size_t)sr * DMODEL + tid, isbf);
  else            v = ((const float*)src)[(size_t)sr * DMODEL + tid];
  res[(size_t)r * DMODEL + tid] = v;
  float s1 = v, s2 = v * v;
#pragma unroll
  for (int o = 32; o > 0; o >>= 1) {
    s1 += __shfl_xor(s1, o, 64);
    s2 += __shfl_xor(s2, o, 64);
  }
  __shared__ float r1[4], r2[4];
  if ((tid & 63) == 0) { r1[tid >> 6] = s1; r2[tid >> 6] = s2; }
  __syncthreads();
  s1 = r1[0] + r1[1] + r1[2] + r1[3];
  s2 = r2[0] + r2[1] + r2[2] + r2[3];
  float mean = s1 * (1.f / DMODEL);
  float var  = s2 * (1.f / DMODEL) - mean * mean;
  float inv  = rsqrtf(var + 1e-5f);
  xn[(size_t)r * DMODEL + tid] = (v - mean) * inv * ldw(g, wo + tid, isbf) + ldw(bta, wo + tid, isbf);
}

// C[M,N] = A[M,K](f32) @ W[K,N] [+ res].
// OUTMODE 0: f32 to ws, 1: final out per flag. WSRC 0: flag dtype, 1: f32 ws.
template<int OUTMODE, int WSRC>
__global__ __launch_bounds__(256) void gemm_kernel(
    const float* __restrict__ A, const void* __restrict__ W, size_t wo,
    const float* __restrict__ res, void* __restrict__ Out,
    const int* __restrict__ pf, int N, int K)
{
  const int isbf = *pf;
  __shared__ float As[64 * 17];
  __shared__ float Ws[16 * 64];
  int tid = threadIdx.x;
  int m0 = blockIdx.y << 6, n0 = blockIdx.x << 6;
  int tx = tid & 15, ty = tid >> 4;
  int lam = tid >> 2, lak = (tid & 3) << 2;
  int lwk = tid >> 4, lwn = (tid & 15) << 2;
  float acc[4][4] = {};
  for (int k0 = 0; k0 < K; k0 += 16) {
    float4 av = *(const float4*)(A + (size_t)(m0 + lam) * K + k0 + lak);
    As[lam * 17 + lak + 0] = av.x;
    As[lam * 17 + lak + 1] = av.y;
    As[lam * 17 + lak + 2] = av.z;
    As[lam * 17 + lak + 3] = av.w;
    size_t woff = wo + (size_t)(k0 + lwk) * N + n0 + lwn;
    if (WSRC == 1) {
      float4 wv = *(const float4*)((const float*)W + woff);
      Ws[lwk * 64 + lwn + 0] = wv.x;
      Ws[lwk * 64 + lwn + 1] = wv.y;
      Ws[lwk * 64 + lwn + 2] = wv.z;
      Ws[lwk * 64 + lwn + 3] = wv.w;
    } else if (isbf) {
      ushort4 wv = *(const ushort4*)((const u16*)W + woff);
      Ws[lwk * 64 + lwn + 0] = bf2f(wv.x);
      Ws[lwk * 64 + lwn + 1] = bf2f(wv.y);
      Ws[lwk * 64 + lwn + 2] = bf2f(wv.z);
      Ws[lwk * 64 + lwn + 3] = bf2f(wv.w);
    } else {
      float4 wv = *(const float4*)((const float*)W + woff);
      Ws[lwk * 64 + lwn + 0] = wv.x;
      Ws[lwk * 64 + lwn + 1] = wv.y;
      Ws[lwk * 64 + lwn + 2] = wv.z;
      Ws[lwk * 64 + lwn + 3] = wv.w;
    }
    __syncthreads();
#pragma unroll
    for (int kk = 0; kk < 16; ++kk) {
      float a0 = As[(ty * 4 + 0) * 17 + kk];
      float a1 = As[(ty * 4 + 1) * 17 + kk];
      float a2 = As[(ty * 4 + 2) * 17 + kk];
      float a3 = As[(ty * 4 + 3) * 17 + kk];
      float4 w4 = *(const float4*)(Ws + kk * 64 + (tx << 2));
      acc[0][0] += a0 * w4.x; acc[0][1] += a0 * w4.y; acc[0][2] += a0 * w4.z; acc[0][3] += a0 * w4.w;
      acc[1][0] += a1 * w4.x; acc[1][1] += a1 * w4.y; acc[1][2] += a1 * w4.z; acc[1][3] += a1 * w4.w;
      acc[2][0] += a2 * w4.x; acc[2][1] += a2 * w4.y; acc[2][2] += a2 * w4.z; acc[2][3] += a2 * w4.w;
      acc[3][0] += a3 * w4.x; acc[3][1] += a3 * w4.y; acc[3][2] += a3 * w4.z; acc[3][3] += a3 * w4.w;
    }
    __syncthreads();
  }
#pragma unroll
  for (int i = 0; i < 4; ++i) {
    int row = m0 + ty * 4 + i;
#pragma unroll
    for (int j = 0; j < 4; ++j) {
      int col = n0 + (tx << 2) + j;
      float v = acc[i][j];
      if (res) v += res[(size_t)row * N + col];
      size_t oidx = (size_t)row * N + col;
      if (OUTMODE == 0) ((float*)Out)[oidx] = v;
      else { if (isbf) ((u16*)Out)[oidx] = f2bf(v); else ((float*)Out)[oidx] = v; }
    }
  }
}

__global__ __launch_bounds__(256) void conv_kernel(
    const float* __restrict__ xz, const void* __restrict__ cw, const void* __restrict__ cb,
    size_t ow, size_t ob, const int* __restrict__ pf, float* __restrict__ xc)
{
  const int isbf = *pf;
  int idx = blockIdx.x * 256 + threadIdx.x;  // 4096*512
  int r = idx >> 9, d = idx & 511;
  int b = r >> 11, s = r & 2047;
  float acc = ldw(cb, ob + d, isbf);
#pragma unroll
  for (int k = 0; k < 4; ++k) {
    int t = s - 3 + k;
    if (t >= 0) acc += ldw(cw, ow + (size_t)d * 4 + k, isbf) * xz[((size_t)(b * S_LEN + t) << 10) + d];
  }
  xc[idx] = siluf(acc);
}

// delta = softplus(dBC[:, 0:32] @ dtp_w + dtp_b)
__global__ __launch_bounds__(256) void skinny2_kernel(
    const float* __restrict__ dBC, const void* __restrict__ dtpw, const void* __restrict__ dtpb,
    size_t ow, size_t ob, const int* __restrict__ pf, float* __restrict__ delta)
{
  const int isbf = *pf;
  int idx = blockIdx.x * 256 + threadIdx.x;
  int r = idx >> 9, d = idx & 511;
  float s = ldw(dtpb, ob + d, isbf);
#pragma unroll 8
  for (int j = 0; j < 32; ++j) s += dBC[(size_t)r * 64 + j] * ldw(dtpw, ow + (size_t)j * 512 + d, isbf);
  delta[idx] = softplusf(s);
}

// Phase 1: per-chunk aggregates, LDS-staged operands.
__global__ __launch_bounds__(256) void scan_chunk_kernel(
    const float* __restrict__ delta, const float* __restrict__ xc, const float* __restrict__ dBC,
    const void* __restrict__ A_log, size_t oA, const int* __restrict__ pf,
    float* __restrict__ aggA, float* __restrict__ aggB)
{
  const int isbf = *pf;
  __shared__ float sd[32][17], sx[32][17], sb[32][17];
  int tid = threadIdx.x;
  int n = tid & 15, dl = tid >> 4;
  int d0 = blockIdx.x << 4;
  int c = blockIdx.y, b = blockIdx.z;
  int row0 = b * S_LEN + c * CLEN;
  for (int l = tid; l < 512; l += 256) {
    int tl = l >> 4, e = l & 15;
    sd[tl][e] = delta[(size_t)(row0 + tl) * DINNER + d0 + e];
    sx[tl][e] = xc[(size_t)(row0 + tl) * DINNER + d0 + e];
    sb[tl][e] = dBC[(size_t)(row0 + tl) * 64 + 32 + e];
  }
  __syncthreads();
  float Ac = -__expf(ldw(A_log, oA + (size_t)(d0 + dl) * 16 + n, isbf));
  float h = 0.f, lacc = 0.f;
#pragma unroll 4
  for (int tt = 0; tt < CLEN; ++tt) {
    float de = sd[tt][dl];
    float xv = sx[tt][dl];
    float bv = sb[tt][n];
    float u = de * Ac;
    h = __expf(u) * h + de * xv * bv;
    lacc += u;
  }
  size_t o = (((size_t)(b * NCHUNK + c) * DINNER) + d0 + dl) * 16 + n;
  aggA[o] = __expf(lacc);
  aggB[o] = h;
}

// Phase 2: exclusive prefix over chunks, in place: aggB becomes hpref.
__global__ __launch_bounds__(256) void scan_prefix_kernel(
    const float* __restrict__ aggA, float* __restrict__ aggB)
{
  int idx = blockIdx.x * 256 + threadIdx.x;  // 2*512*16
  int n = idx & 15, d = (idx >> 4) & 511, b = idx >> 13;
  float h = 0.f;
  for (int c = 0; c < NCHUNK; ++c) {
    size_t o = (((size_t)(b * NCHUNK + c) * DINNER) + d) * 16 + n;
    float a = aggA[o], t = aggB[o];
    aggB[o] = h;
    h = a * h + t;
  }
}

// Phase 3: replay with true initial state; LDS-staged; coalesced ym write.
__global__ __launch_bounds__(256) void scan_apply_kernel(
    const float* __restrict__ delta, const float* __restrict__ xc, const float* __restrict__ dBC,
    const float* __restrict__ xz, const float* __restrict__ hpref,
    const void* __restrict__ A_log, size_t oA, const void* __restrict__ Dp, size_t oD,
    const int* __restrict__ pf, float* __restrict__ ym)
{
  const int isbf = *pf;
  __shared__ float sd[32][17], sx[32][17], sb[32][17], sc[32][17], sz[32][17], sy[32][17];
  int tid = threadIdx.x;
  int n = tid & 15, dl = tid >> 4;
  int d0 = blockIdx.x << 4;
  int c = blockIdx.y, b = blockIdx.z;
  int row0 = b * S_LEN + c * CLEN;
  for (int l = tid; l < 512; l += 256) {
    int tl = l >> 4, e = l & 15;
    size_t rr = (size_t)(row0 + tl);
    sd[tl][e] = delta[rr * DINNER + d0 + e];
    sx[tl][e] = xc[rr * DINNER + d0 + e];
    sb[tl][e] = dBC[rr * 64 + 32 + e];
    sc[tl][e] = dBC[rr * 64 + 48 + e];
    sz[tl][e] = xz[(rr << 10) + 512 + d0 + e];
  }
  __syncthreads();
  float Ac = -__expf(ldw(A_log, oA + (size_t)(d0 + dl) * 16 + n, isbf));
  size_t o = (((size_t)(b * NCHUNK + c) * DINNER) + d0 + dl) * 16 + n;
  float h = hpref[o];
  float Dv = ldw(Dp, oD + d0 + dl, isbf);
#pragma unroll 4
  for (int tt = 0; tt < CLEN; ++tt) {
    float de = sd[tt][dl];
    float xv = sx[tt][dl];
    float bv = sb[tt][n];
    float cv = sc[tt][n];
    h = __expf(de * Ac) * h + de * xv * bv;
    float yc = h * cv;
    yc += __shfl_xor(yc, 1, 64);
    yc += __shfl_xor(yc, 2, 64);
    yc += __shfl_xor(yc, 4, 64);
    yc += __shfl_xor(yc, 8, 64);
    if (n == 0) sy[tt][dl] = yc + Dv * xv;
  }
  __syncthreads();
  for (int l = tid; l < 512; l += 256) {
    int tl = l >> 4, e = l & 15;
    ym[(size_t)(row0 + tl) * DINNER + d0 + e] = sy[tl][e] * siluf(sz[tl][e]);
  }
}

__global__ __launch_bounds__(256) void cat_kernel(
    const float* __restrict__ ofwd, const float* __restrict__ obwd, float* __restrict__ cat)
{
  int idx = blockIdx.x * 256 + threadIdx.x;
  int r = idx >> 9, ccol = idx & 511;
  int b = r >> 11, s = r & 2047;
  float v;
  if (ccol < 256) v = ofwd[(size_t)r * 256 + ccol];
  else v = obwd[(size_t)(b * S_LEN + (S_LEN - 1 - s)) * 256 + (ccol - 256)];
  cat[idx] = v;
}

extern "C" void kernel_launch(void* const* d_in, const int* in_sizes, int n_in,
                              void* d_out, int out_size, void* d_ws, size_t ws_size,
                              hipStream_t stream)
{
  const void* x       = d_in[0];
  const void* in_w    = d_in[1];
  const void* conv_w  = d_in[2];
  const void* conv_b  = d_in[3];
  const void* A_log   = d_in[4];
  const void* xd_w    = d_in[5];
  const void* xB_w    = d_in[6];
  const void* xC_w    = d_in[7];
  const void* dtp_w   = d_in[8];
  const void* dtp_b   = d_in[9];
  const void* Dp      = d_in[10];
  const void* out_w   = d_in[11];
  const void* ln_g    = d_in[12];
  const void* ln_b    = d_in[13];
  const void* merge_w = d_in[14];

  const size_t M = 4096;
  float* ws = (float*)d_ws;
  float* res   = ws;                          // 1M floats
  float* dxn   = res + M * 256;               // 2M: xn then delta (disjoint lifetimes)
  float* xn    = dxn;
  float* delta = dxn;
  float* xz    = dxn + M * 512;               // 4M
  float* xc    = xz + M * 1024;               // 2M
  float* dBC   = xc + M * 512;                // 256K: [4096][64] = delta_tmp|B|C
  float* aggA  = dBC + M * 64;                // 1M
  float* aggB  = aggA + (size_t)2 * NCHUNK * DINNER * 16;  // 1M (becomes hpref)
  float* ymb   = aggB + (size_t)2 * NCHUNK * DINNER * 16;  // 2M
  float* obA   = ymb + M * 512;               // 1M (blocks 0 and 2)
  float* ob1   = obA + M * 256;               // 1M
  float* ob3   = ob1 + M * 256;               // 1M
  float* Wall  = ob3 + M * 256;               // 128K: [4][512][64]
  int*   flagp = (int*)(Wall + 4 * 512 * 64);
  float* catb  = xz;                          // xz free by merge time

  dim3 blk(256);
  hipLaunchKernelGGL(detect_kernel, dim3(1), blk, 0, stream, x, flagp);
  hipLaunchKernelGGL(pack_kernel, dim3(512), blk, 0, stream, xd_w, xB_w, xC_w, flagp, Wall);

  for (int i = 0; i < 4; ++i) {
    const void* src; int ext, rev; float* dst;
    if (i == 0)      { src = x;   ext = 1; rev = 0; dst = obA; }
    else if (i == 1) { src = obA; ext = 0; rev = 0; dst = ob1; }
    else if (i == 2) { src = x;   ext = 1; rev = 1; dst = obA; }
    else             { src = obA; ext = 0; rev = 0; dst = ob3; }

    hipLaunchKernelGGL(ln_kernel, dim3(4096), blk, 0, stream,
        src, ext, rev, ln_g, ln_b, (size_t)i * 256, flagp, res, xn);
    hipLaunchKernelGGL((gemm_kernel<0, 0>), dim3(16, 64), blk, 0, stream,
        xn, in_w, (size_t)i * 256 * 1024, (const float*)nullptr, (void*)xz, flagp, 1024, 256);
    hipLaunchKernelGGL(conv_kernel, dim3(8192), blk, 0, stream,
        xz, conv_w, conv_b, (size_t)i * 512 * 4, (size_t)i * 512, flagp, xc);
    hipLaunchKernelGGL((gemm_kernel<0, 1>), dim3(1, 64), blk, 0, stream,
        xc, (const void*)Wall, (size_t)i * 512 * 64, (const float*)nullptr, (void*)dBC,
        flagp, 64, 512);
    hipLaunchKernelGGL(skinny2_kernel, dim3(8192), blk, 0, stream,
        dBC, dtp_w, dtp_b, (size_t)i * 32 * 512, (size_t)i * 512, flagp, delta);
    hipLaunchKernelGGL(scan_chunk_kernel, dim3(32, 64, 2), blk, 0, stream,
        delta, xc, dBC, A_log, (size_t)i * 512 * 16, flagp, aggA, aggB);
    hipLaunchKernelGGL(scan_prefix_kernel, dim3(64), blk, 0, stream, aggA, aggB);
    hipLaunchKernelGGL(scan_apply_kernel, dim3(32, 64, 2), blk, 0, stream,
        delta, xc, dBC, xz, aggB, A_log, (size_t)i * 512 * 16, Dp, (size_t)i * 512,
        flagp, ymb);
    hipLaunchKernelGGL((gemm_kernel<0, 0>), dim3(4, 64), blk, 0, stream,
        ymb, out_w, (size_t)i * 512 * 256, res, (void*)dst, flagp, 256, 512);
  }
  hipLaunchKernelGGL(cat_kernel, dim3(8192), blk, 0, stream, ob1, ob3, catb);
  hipLaunchKernelGGL((gemm_kernel<1, 0>), dim3(4, 64), blk, 0, stream,
      catb, merge_w, (size_t)0, (const float*)nullptr, d_out, flagp, 256, 512);
}

// Round 6
// 731.415 us; speedup vs baseline: 1.5978x; 1.2984x over previous
//
#include <hip/hip_runtime.h>

#define S_LEN 2048
#define DMODEL 256
#define DINNER 512
#define NCHUNK 64
#define CLEN 32

typedef unsigned short u16;
typedef short bf16x8 __attribute__((ext_vector_type(8)));
typedef unsigned short u16x8 __attribute__((ext_vector_type(8)));  // 16 bytes
typedef float f32x4 __attribute__((ext_vector_type(4)));

__device__ __forceinline__ float bf2f(u16 u) {
  unsigned int x = ((unsigned int)u) << 16;
  float f; __builtin_memcpy(&f, &x, 4); return f;
}
__device__ __forceinline__ u16 f2bf(float f) {
  unsigned int x; __builtin_memcpy(&x, &f, 4);
  return (u16)((x + 0x7FFFu + ((x >> 16) & 1u)) >> 16);
}
__device__ __forceinline__ float ldw(const void* p, size_t i, int isbf) {
  return isbf ? bf2f(((const u16*)p)[i]) : ((const float*)p)[i];
}
__device__ __forceinline__ float siluf(float x) { return x / (1.f + __expf(-x)); }
__device__ __forceinline__ float softplusf(float x) {
  if (x > 20.f) return x;
  return log1pf(__expf(x));
}

// Detect input dtype (bf16 vs f32) from exponent-byte statistics.
__global__ __launch_bounds__(256) void detect_kernel(const void* __restrict__ x,
                                                     int* __restrict__ flag) {
  __shared__ int cnt;
  if (threadIdx.x == 0) cnt = 0;
  __syncthreads();
  u16 u = ((const u16*)x)[2 * threadIdx.x];
  int e = (u >> 7) & 0xFF;
  if (e >= 0x60 && e <= 0x8F) atomicAdd(&cnt, 1);
  __syncthreads();
  if (threadIdx.x == 0) *flag = (cnt > 128) ? 1 : 0;
}

// ---------------- weight pre-pack into MFMA fragment order ----------------
// Packed W[K][N]: chunk c = n_blk16*(K/32) + k_blk32, 512 bf16 per chunk;
// inside: q*128 + (n&15)*8 + (k&7). B-frag read = contiguous ds_read_b128.
__global__ __launch_bounds__(256) void wpack_kernel(
    const void* __restrict__ src, const int* __restrict__ pf,
    u16* __restrict__ dst, int K, int N)
{
  const int isbf = *pf;
  __shared__ float tile[32][65];
  int nb64 = blockIdx.x, kb = blockIdx.y, mat = blockIdx.z;
  size_t so = (size_t)mat * K * N;
  int tid = threadIdx.x;
  int kk = tid >> 3, nseg = (tid & 7) * 8;
#pragma unroll
  for (int j = 0; j < 8; ++j)
    tile[kk][nseg + j] = ldw(src, so + (size_t)(kb * 32 + kk) * N + nb64 * 64 + nseg + j, isbf);
  __syncthreads();
  int cc = tid >> 6, i0 = (tid & 63) * 8;
  int q = i0 >> 7, nn = (i0 >> 3) & 15;
  u16 outv[8];
#pragma unroll
  for (int j = 0; j < 8; ++j) outv[j] = f2bf(tile[q * 8 + j][cc * 16 + nn]);
  size_t doff = (size_t)mat * K * N + ((size_t)(nb64 * 4 + cc) * (K >> 5) + kb) * 512 + i0;
  *(u16x8*)(dst + doff) = *(const u16x8*)outv;
}

// Fused xd_w|xB_w|xC_w -> packed [4][512][64] (K=512, N=64).
__global__ __launch_bounds__(256) void wpack_fused_kernel(
    const void* __restrict__ xdw, const void* __restrict__ xBw, const void* __restrict__ xCw,
    const int* __restrict__ pf, u16* __restrict__ dst)
{
  const int isbf = *pf;
  __shared__ float tile[32][65];
  int kb = blockIdx.y, mat = blockIdx.z;
  int tid = threadIdx.x;
  int kk = tid >> 3, nseg = (tid & 7) * 8;
  int k = kb * 32 + kk;
#pragma unroll
  for (int j = 0; j < 8; ++j) {
    int n = nseg + j; float v;
    if (n < 32)      v = ldw(xdw, (size_t)mat * 16384 + (size_t)k * 32 + n, isbf);
    else if (n < 48) v = ldw(xBw, (size_t)mat * 8192 + (size_t)k * 16 + (n - 32), isbf);
    else             v = ldw(xCw, (size_t)mat * 8192 + (size_t)k * 16 + (n - 48), isbf);
    tile[kk][n] = v;
  }
  __syncthreads();
  int cc = tid >> 6, i0 = (tid & 63) * 8;
  int q = i0 >> 7, nn = (i0 >> 3) & 15;
  u16 outv[8];
#pragma unroll
  for (int j = 0; j < 8; ++j) outv[j] = f2bf(tile[q * 8 + j][cc * 16 + nn]);
  size_t doff = (size_t)mat * 512 * 64 + ((size_t)cc * 16 + kb) * 512 + i0;
  *(u16x8*)(dst + doff) = *(const u16x8*)outv;
}

// ---------------- LayerNorm: residual f32 + bf16 normalized out ----------------
__global__ __launch_bounds__(256) void ln_kernel(
    const void* __restrict__ src, int src_is_ext, int rev,
    const void* __restrict__ g, const void* __restrict__ bta, size_t wo,
    const int* __restrict__ pf, float* __restrict__ res, u16* __restrict__ xnb)
{
  const int isbf = *pf;
  int r = blockIdx.x;
  int tid = threadIdx.x;
  int b = r >> 11, s = r & 2047;
  int sr = rev ? (b * S_LEN + (S_LEN - 1 - s)) : r;
  float v;
  if (src_is_ext) v = ldw(src, (size_t)sr * DMODEL + tid, isbf);
  else            v = ((const float*)src)[(size_t)sr * DMODEL + tid];
  res[(size_t)r * DMODEL + tid] = v;
  float s1 = v, s2 = v * v;
#pragma unroll
  for (int o = 32; o > 0; o >>= 1) {
    s1 += __shfl_xor(s1, o, 64);
    s2 += __shfl_xor(s2, o, 64);
  }
  __shared__ float r1[4], r2[4];
  if ((tid & 63) == 0) { r1[tid >> 6] = s1; r2[tid >> 6] = s2; }
  __syncthreads();
  s1 = r1[0] + r1[1] + r1[2] + r1[3];
  s2 = r2[0] + r2[1] + r2[2] + r2[3];
  float mean = s1 * (1.f / DMODEL);
  float var  = s2 * (1.f / DMODEL) - mean * mean;
  float inv  = rsqrtf(var + 1e-5f);
  xnb[(size_t)r * DMODEL + tid] =
      f2bf((v - mean) * inv * ldw(g, wo + tid, isbf) + ldw(bta, wo + tid, isbf));
}

// ---------------- MFMA GEMM: C[M,N] = A(bf16 row-major) @ Wp(packed) [+res] ----------
// BM=128, BK=32, 256 thr = 4 waves. BN=128: waves 2x2 (64x64 each). BN=64: 4x1.
// OUTMODE 0: f32. 1: final dtype per flag. 2: bf16.
template<int BN, int OUTMODE>
__global__ __launch_bounds__(256) void mfma_gemm(
    const u16* __restrict__ A, const u16* __restrict__ Wp, size_t wo,
    const float* __restrict__ res, void* __restrict__ Out,
    const int* __restrict__ pf, int N, int K)
{
  const int isbf = *pf;
  __shared__ __align__(16) u16 Asb[128 * 32];
  __shared__ __align__(16) u16 Bsb[BN * 32];
  int tid = threadIdx.x;
  int n0 = blockIdx.x * BN, m0 = blockIdx.y * 128;
  int w = tid >> 6, lane = tid & 63;
  int q = lane >> 4, r = lane & 15;
  constexpr int WM = (BN == 128) ? 4 : 2;
  const int wm0 = (BN == 128) ? ((w >> 1) * 4) : (w * 2);
  const int wn0 = (BN == 128) ? ((w & 1) * 4) : 0;
  f32x4 acc[WM][4];
#pragma unroll
  for (int i = 0; i < WM; ++i)
#pragma unroll
    for (int j = 0; j < 4; ++j) acc[i][j] = (f32x4){0.f, 0.f, 0.f, 0.f};

  const int kbs = K >> 5;
  // A staging: thread t stages 16 u16 of row m = t>>1 (two 8-elem frag rows).
  int sm = tid >> 1, sq = (tid & 1) * 2;
  const u16* arow = A + (size_t)(m0 + sm) * K + sq * 8;
  u16* adst0 = Asb + ((sm >> 4) * 4 + sq) * 128 + (sm & 15) * 8;
  u16* adst1 = Asb + ((sm >> 4) * 4 + sq + 1) * 128 + (sm & 15) * 8;

  for (int k0 = 0; k0 < K; k0 += 32) {
    u16x8 a0 = *(const u16x8*)(arow + k0);
    u16x8 a1 = *(const u16x8*)(arow + k0 + 8);
    *(u16x8*)adst0 = a0;
    *(u16x8*)adst1 = a1;
#pragma unroll
    for (int p = tid; p < BN * 4; p += 256) {
      int nb = p >> 6, inner = (p & 63) * 8;
      const u16* srcb = Wp + wo + ((size_t)((n0 >> 4) + nb) * kbs + (k0 >> 5)) * 512 + inner;
      *(u16x8*)(Bsb + nb * 512 + inner) = *(const u16x8*)srcb;
    }
    __syncthreads();
    bf16x8 af[WM], bfr[4];
#pragma unroll
    for (int i = 0; i < WM; ++i)
      af[i] = *(const bf16x8*)(Asb + ((wm0 + i) * 4 + q) * 128 + r * 8);
#pragma unroll
    for (int j = 0; j < 4; ++j)
      bfr[j] = *(const bf16x8*)(Bsb + ((wn0 + j) * 4 + q) * 128 + r * 8);
#pragma unroll
    for (int i = 0; i < WM; ++i)
#pragma unroll
      for (int j = 0; j < 4; ++j)
        acc[i][j] = __builtin_amdgcn_mfma_f32_16x16x32_bf16(af[i], bfr[j], acc[i][j], 0, 0, 0);
    __syncthreads();
  }
#pragma unroll
  for (int i = 0; i < WM; ++i) {
    int rowb = m0 + (wm0 + i) * 16 + q * 4;
#pragma unroll
    for (int j = 0; j < 4; ++j) {
      int col = n0 + (wn0 + j) * 16 + r;
#pragma unroll
      for (int t = 0; t < 4; ++t) {
        int row = rowb + t;
        float v = acc[i][j][t];
        size_t oidx = (size_t)row * N + col;
        if (res) v += res[oidx];
        if (OUTMODE == 0)      ((float*)Out)[oidx] = v;
        else if (OUTMODE == 2) ((u16*)Out)[oidx] = f2bf(v);
        else { if (isbf) ((u16*)Out)[oidx] = f2bf(v); else ((float*)Out)[oidx] = v; }
      }
    }
  }
}

// ---------------- causal depthwise conv K=4 + bias + SiLU (bf16 in/out) -------------
__global__ __launch_bounds__(256) void conv_kernel(
    const u16* __restrict__ xzb, const void* __restrict__ cw, const void* __restrict__ cb,
    size_t ow, size_t ob, const int* __restrict__ pf, u16* __restrict__ xcb)
{
  const int isbf = *pf;
  int idx = blockIdx.x * 256 + threadIdx.x;  // 4096*512
  int r = idx >> 9, d = idx & 511;
  int b = r >> 11, s = r & 2047;
  float acc = ldw(cb, ob + d, isbf);
#pragma unroll
  for (int k = 0; k < 4; ++k) {
    int t = s - 3 + k;
    if (t >= 0)
      acc += ldw(cw, ow + (size_t)d * 4 + k, isbf) * bf2f(xzb[((size_t)(b * S_LEN + t) << 10) + d]);
  }
  xcb[idx] = f2bf(siluf(acc));
}

// delta = softplus(dBC[:, 0:32] @ dtp_w + dtp_b)
__global__ __launch_bounds__(256) void skinny2_kernel(
    const float* __restrict__ dBC, const void* __restrict__ dtpw, const void* __restrict__ dtpb,
    size_t ow, size_t ob, const int* __restrict__ pf, float* __restrict__ delta)
{
  const int isbf = *pf;
  int idx = blockIdx.x * 256 + threadIdx.x;
  int r = idx >> 9, d = idx & 511;
  float s = ldw(dtpb, ob + d, isbf);
#pragma unroll 8
  for (int j = 0; j < 32; ++j) s += dBC[(size_t)r * 64 + j] * ldw(dtpw, ow + (size_t)j * 512 + d, isbf);
  delta[idx] = softplusf(s);
}

// Phase 1: per-chunk scan aggregates (LDS-staged).
__global__ __launch_bounds__(256) void scan_chunk_kernel(
    const float* __restrict__ delta, const u16* __restrict__ xcb, const float* __restrict__ dBC,
    const void* __restrict__ A_log, size_t oA, const int* __restrict__ pf,
    float* __restrict__ aggA, float* __restrict__ aggB)
{
  const int isbf = *pf;
  __shared__ float sd[32][17], sx[32][17], sb[32][17];
  int tid = threadIdx.x;
  int n = tid & 15, dl = tid >> 4;
  int d0 = blockIdx.x << 4;
  int c = blockIdx.y, b = blockIdx.z;
  int row0 = b * S_LEN + c * CLEN;
  for (int l = tid; l < 512; l += 256) {
    int tl = l >> 4, e = l & 15;
    sd[tl][e] = delta[(size_t)(row0 + tl) * DINNER + d0 + e];
    sx[tl][e] = bf2f(xcb[(size_t)(row0 + tl) * DINNER + d0 + e]);
    sb[tl][e] = dBC[(size_t)(row0 + tl) * 64 + 32 + e];
  }
  __syncthreads();
  float Ac = -__expf(ldw(A_log, oA + (size_t)(d0 + dl) * 16 + n, isbf));
  float h = 0.f, lacc = 0.f;
#pragma unroll 4
  for (int tt = 0; tt < CLEN; ++tt) {
    float de = sd[tt][dl];
    float xv = sx[tt][dl];
    float bv = sb[tt][n];
    float u = de * Ac;
    h = __expf(u) * h + de * xv * bv;
    lacc += u;
  }
  size_t o = (((size_t)(b * NCHUNK + c) * DINNER) + d0 + dl) * 16 + n;
  aggA[o] = __expf(lacc);
  aggB[o] = h;
}

// Phase 2: exclusive prefix over chunks in place (aggB -> hpref).
__global__ __launch_bounds__(256) void scan_prefix_kernel(
    const float* __restrict__ aggA, float* __restrict__ aggB)
{
  int idx = blockIdx.x * 256 + threadIdx.x;
  int n = idx & 15, d = (idx >> 4) & 511, b = idx >> 13;
  float h = 0.f;
  for (int c = 0; c < NCHUNK; ++c) {
    size_t o = (((size_t)(b * NCHUNK + c) * DINNER) + d) * 16 + n;
    float a = aggA[o], t = aggB[o];
    aggB[o] = h;
    h = a * h + t;
  }
}

// Phase 3: replay with true initial state; gated bf16 output for out-proj A.
__global__ __launch_bounds__(256) void scan_apply_kernel(
    const float* __restrict__ delta, const u16* __restrict__ xcb, const float* __restrict__ dBC,
    const u16* __restrict__ xzb, const float* __restrict__ hpref,
    const void* __restrict__ A_log, size_t oA, const void* __restrict__ Dp, size_t oD,
    const int* __restrict__ pf, u16* __restrict__ ymb)
{
  const int isbf = *pf;
  __shared__ float sd[32][17], sx[32][17], sb[32][17], sc[32][17], sz[32][17], sy[32][17];
  int tid = threadIdx.x;
  int n = tid & 15, dl = tid >> 4;
  int d0 = blockIdx.x << 4;
  int c = blockIdx.y, b = blockIdx.z;
  int row0 = b * S_LEN + c * CLEN;
  for (int l = tid; l < 512; l += 256) {
    int tl = l >> 4, e = l & 15;
    size_t rr = (size_t)(row0 + tl);
    sd[tl][e] = delta[rr * DINNER + d0 + e];
    sx[tl][e] = bf2f(xcb[rr * DINNER + d0 + e]);
    sb[tl][e] = dBC[rr * 64 + 32 + e];
    sc[tl][e] = dBC[rr * 64 + 48 + e];
    sz[tl][e] = bf2f(xzb[(rr << 10) + 512 + d0 + e]);
  }
  __syncthreads();
  float Ac = -__expf(ldw(A_log, oA + (size_t)(d0 + dl) * 16 + n, isbf));
  size_t o = (((size_t)(b * NCHUNK + c) * DINNER) + d0 + dl) * 16 + n;
  float h = hpref[o];
  float Dv = ldw(Dp, oD + d0 + dl, isbf);
#pragma unroll 4
  for (int tt = 0; tt < CLEN; ++tt) {
    float de = sd[tt][dl];
    float xv = sx[tt][dl];
    float bv = sb[tt][n];
    float cv = sc[tt][n];
    h = __expf(de * Ac) * h + de * xv * bv;
    float yc = h * cv;
    yc += __shfl_xor(yc, 1, 64);
    yc += __shfl_xor(yc, 2, 64);
    yc += __shfl_xor(yc, 4, 64);
    yc += __shfl_xor(yc, 8, 64);
    if (n == 0) sy[tt][dl] = yc + Dv * xv;
  }
  __syncthreads();
  for (int l = tid; l < 512; l += 256) {
    int tl = l >> 4, e = l & 15;
    ymb[(size_t)(row0 + tl) * DINNER + d0 + e] = f2bf(sy[tl][e] * siluf(sz[tl][e]));
  }
}

// concat fwd|bwd(un-reversed) -> bf16 merge-GEMM A operand
__global__ __launch_bounds__(256) void cat_kernel(
    const float* __restrict__ ofwd, const float* __restrict__ obwd, u16* __restrict__ cat)
{
  int idx = blockIdx.x * 256 + threadIdx.x;
  int r = idx >> 9, ccol = idx & 511;
  int b = r >> 11, s = r & 2047;
  float v;
  if (ccol < 256) v = ofwd[(size_t)r * 256 + ccol];
  else v = obwd[(size_t)(b * S_LEN + (S_LEN - 1 - s)) * 256 + (ccol - 256)];
  cat[idx] = f2bf(v);
}

extern "C" void kernel_launch(void* const* d_in, const int* in_sizes, int n_in,
                              void* d_out, int out_size, void* d_ws, size_t ws_size,
                              hipStream_t stream)
{
  const void* x       = d_in[0];
  const void* in_w    = d_in[1];
  const void* conv_w  = d_in[2];
  const void* conv_b  = d_in[3];
  const void* A_log   = d_in[4];
  const void* xd_w    = d_in[5];
  const void* xB_w    = d_in[6];
  const void* xC_w    = d_in[7];
  const void* dtp_w   = d_in[8];
  const void* dtp_b   = d_in[9];
  const void* Dp      = d_in[10];
  const void* out_w   = d_in[11];
  const void* ln_g    = d_in[12];
  const void* ln_b    = d_in[13];
  const void* merge_w = d_in[14];

  const size_t M = 4096;
  // ---- workspace (~50.5 MB; proven-safe >= 65.5 MB) ----
  float* ws    = (float*)d_ws;
  float* res   = ws;                                        // 1.00 M floats
  float* delta = res + M * 256;                             // 2.00 M
  float* dBC   = delta + M * 512;                           // 0.25 M
  float* aggA  = dBC + M * 64;                              // 1.00 M (ym_bf alias)
  float* aggB  = aggA + (size_t)2 * NCHUNK * DINNER * 16;   // 1.00 M (-> hpref)
  float* obA   = aggB + (size_t)2 * NCHUNK * DINNER * 16;   // 1.00 M (blocks 0,2)
  float* ob1   = obA + M * 256;                             // 1.00 M
  float* ob3   = ob1 + M * 256;                             // 1.00 M
  u16*   xn_bf = (u16*)(ob3 + M * 256);                     // 1 M u16
  u16*   xz_bf = xn_bf + M * 256;                           // 4 M u16
  u16*   xc_bf = xz_bf + M * 1024;                          // 2 M u16
  u16*   Wp_in = xc_bf + M * 512;                           // 1 M u16
  u16*   Wp_out= Wp_in + (size_t)4 * 256 * 1024;            // 0.5 M u16
  u16*   Wp_mg = Wp_out + (size_t)4 * 512 * 256;            // 128 K u16
  u16*   Wp_all= Wp_mg + (size_t)512 * 256;                 // 128 K u16
  int*   flagp = (int*)(Wp_all + (size_t)4 * 512 * 64);
  u16*   ym_bf = (u16*)aggA;     // alias: aggA dead after scan_prefix
  u16*   cat_bf= (u16*)delta;    // alias: delta dead after last scan_apply

  dim3 blk(256);
  hipLaunchKernelGGL(detect_kernel, dim3(1), blk, 0, stream, x, flagp);
  hipLaunchKernelGGL(wpack_kernel, dim3(16, 8, 4), blk, 0, stream, in_w, flagp, Wp_in, 256, 1024);
  hipLaunchKernelGGL(wpack_kernel, dim3(4, 16, 4), blk, 0, stream, out_w, flagp, Wp_out, 512, 256);
  hipLaunchKernelGGL(wpack_kernel, dim3(4, 16, 1), blk, 0, stream, merge_w, flagp, Wp_mg, 512, 256);
  hipLaunchKernelGGL(wpack_fused_kernel, dim3(1, 16, 4), blk, 0, stream,
      xd_w, xB_w, xC_w, flagp, Wp_all);

  for (int i = 0; i < 4; ++i) {
    const void* src; int ext, rev; float* dst;
    if (i == 0)      { src = x;   ext = 1; rev = 0; dst = obA; }
    else if (i == 1) { src = obA; ext = 0; rev = 0; dst = ob1; }
    else if (i == 2) { src = x;   ext = 1; rev = 1; dst = obA; }
    else             { src = obA; ext = 0; rev = 0; dst = ob3; }

    hipLaunchKernelGGL(ln_kernel, dim3(4096), blk, 0, stream,
        src, ext, rev, ln_g, ln_b, (size_t)i * 256, flagp, res, xn_bf);
    hipLaunchKernelGGL((mfma_gemm<128, 2>), dim3(8, 32), blk, 0, stream,
        xn_bf, Wp_in, (size_t)i * 256 * 1024, (const float*)nullptr, (void*)xz_bf,
        flagp, 1024, 256);
    hipLaunchKernelGGL(conv_kernel, dim3(8192), blk, 0, stream,
        xz_bf, conv_w, conv_b, (size_t)i * 512 * 4, (size_t)i * 512, flagp, xc_bf);
    hipLaunchKernelGGL((mfma_gemm<64, 0>), dim3(1, 32), blk, 0, stream,
        xc_bf, Wp_all, (size_t)i * 512 * 64, (const float*)nullptr, (void*)dBC,
        flagp, 64, 512);
    hipLaunchKernelGGL(skinny2_kernel, dim3(8192), blk, 0, stream,
        dBC, dtp_w, dtp_b, (size_t)i * 32 * 512, (size_t)i * 512, flagp, delta);
    hipLaunchKernelGGL(scan_chunk_kernel, dim3(32, 64, 2), blk, 0, stream,
        delta, xc_bf, dBC, A_log, (size_t)i * 512 * 16, flagp, aggA, aggB);
    hipLaunchKernelGGL(scan_prefix_kernel, dim3(64), blk, 0, stream, aggA, aggB);
    hipLaunchKernelGGL(scan_apply_kernel, dim3(32, 64, 2), blk, 0, stream,
        delta, xc_bf, dBC, xz_bf, aggB, A_log, (size_t)i * 512 * 16, Dp, (size_t)i * 512,
        flagp, ym_bf);
    hipLaunchKernelGGL((mfma_gemm<128, 0>), dim3(2, 32), blk, 0, stream,
        ym_bf, Wp_out, (size_t)i * 512 * 256, res, (void*)dst, flagp, 256, 512);
  }
  hipLaunchKernelGGL(cat_kernel, dim3(8192), blk, 0, stream, ob1, ob3, cat_bf);
  hipLaunchKernelGGL((mfma_gemm<128, 1>), dim3(2, 32), blk, 0, stream,
      cat_bf, Wp_mg, (size_t)0, (const float*)nullptr, d_out, flagp, 256, 512);
}

// Round 8
// 721.781 us; speedup vs baseline: 1.6192x; 1.0133x over previous
//
#include <hip/hip_runtime.h>

#define S_LEN 2048
#define DMODEL 256
#define DINNER 512
#define NCHUNK 64
#define CLEN 32

typedef unsigned short u16;
typedef short bf16x8 __attribute__((ext_vector_type(8)));
typedef unsigned short u16x8 __attribute__((ext_vector_type(8)));  // 16 bytes
typedef float f32x4 __attribute__((ext_vector_type(4)));

__device__ __forceinline__ float bf2f(u16 u) {
  unsigned int x = ((unsigned int)u) << 16;
  float f; __builtin_memcpy(&f, &x, 4); return f;
}
__device__ __forceinline__ u16 f2bf(float f) {
  unsigned int x; __builtin_memcpy(&x, &f, 4);
  return (u16)((x + 0x7FFFu + ((x >> 16) & 1u)) >> 16);
}
__device__ __forceinline__ float ldw(const void* p, size_t i, int isbf) {
  return isbf ? bf2f(((const u16*)p)[i]) : ((const float*)p)[i];
}
__device__ __forceinline__ float siluf(float x) { return x / (1.f + __expf(-x)); }
__device__ __forceinline__ float softplusf(float x) {
  if (x > 20.f) return x;
  return log1pf(__expf(x));
}

// Detect input dtype (bf16 vs f32) from exponent-byte statistics.
__global__ __launch_bounds__(256) void detect_kernel(const void* __restrict__ x,
                                                     int* __restrict__ flag) {
  __shared__ int cnt;
  if (threadIdx.x == 0) cnt = 0;
  __syncthreads();
  u16 u = ((const u16*)x)[2 * threadIdx.x];
  int e = (u >> 7) & 0xFF;
  if (e >= 0x60 && e <= 0x8F) atomicAdd(&cnt, 1);
  __syncthreads();
  if (threadIdx.x == 0) *flag = (cnt > 128) ? 1 : 0;
}

// ---------------- weight pre-pack into MFMA fragment order ----------------
// Packed W[K][N]: chunk c = n_blk16*(K/32) + k_blk32, 512 bf16 per chunk;
// inside: q*128 + (n&15)*8 + (k&7). B-frag read = contiguous ds_read_b128.
__global__ __launch_bounds__(256) void wpack_kernel(
    const void* __restrict__ src, const int* __restrict__ pf,
    u16* __restrict__ dst, int K, int N)
{
  const int isbf = *pf;
  __shared__ float tile[32][65];
  int nb64 = blockIdx.x, kb = blockIdx.y, mat = blockIdx.z;
  size_t so = (size_t)mat * K * N;
  int tid = threadIdx.x;
  int kk = tid >> 3, nseg = (tid & 7) * 8;
#pragma unroll
  for (int j = 0; j < 8; ++j)
    tile[kk][nseg + j] = ldw(src, so + (size_t)(kb * 32 + kk) * N + nb64 * 64 + nseg + j, isbf);
  __syncthreads();
  int cc = tid >> 6, i0 = (tid & 63) * 8;
  int q = i0 >> 7, nn = (i0 >> 3) & 15;
  u16 outv[8];
#pragma unroll
  for (int j = 0; j < 8; ++j) outv[j] = f2bf(tile[q * 8 + j][cc * 16 + nn]);
  size_t doff = (size_t)mat * K * N + ((size_t)(nb64 * 4 + cc) * (K >> 5) + kb) * 512 + i0;
  *(u16x8*)(dst + doff) = *(const u16x8*)outv;
}

// Fused xd_w|xB_w|xC_w -> packed [4][512][64] (K=512, N=64).
__global__ __launch_bounds__(256) void wpack_fused_kernel(
    const void* __restrict__ xdw, const void* __restrict__ xBw, const void* __restrict__ xCw,
    const int* __restrict__ pf, u16* __restrict__ dst)
{
  const int isbf = *pf;
  __shared__ float tile[32][65];
  int kb = blockIdx.y, mat = blockIdx.z;
  int tid = threadIdx.x;
  int kk = tid >> 3, nseg = (tid & 7) * 8;
  int k = kb * 32 + kk;
#pragma unroll
  for (int j = 0; j < 8; ++j) {
    int n = nseg + j; float v;
    if (n < 32)      v = ldw(xdw, (size_t)mat * 16384 + (size_t)k * 32 + n, isbf);
    else if (n < 48) v = ldw(xBw, (size_t)mat * 8192 + (size_t)k * 16 + (n - 32), isbf);
    else             v = ldw(xCw, (size_t)mat * 8192 + (size_t)k * 16 + (n - 48), isbf);
    tile[kk][n] = v;
  }
  __syncthreads();
  int cc = tid >> 6, i0 = (tid & 63) * 8;
  int q = i0 >> 7, nn = (i0 >> 3) & 15;
  u16 outv[8];
#pragma unroll
  for (int j = 0; j < 8; ++j) outv[j] = f2bf(tile[q * 8 + j][cc * 16 + nn]);
  size_t doff = (size_t)mat * 512 * 64 + ((size_t)cc * 16 + kb) * 512 + i0;
  *(u16x8*)(dst + doff) = *(const u16x8*)outv;
}

// ---------------- LayerNorm: residual f32 + bf16 normalized out ----------------
__global__ __launch_bounds__(256) void ln_kernel(
    const void* __restrict__ src, int src_is_ext, int rev,
    const void* __restrict__ g, const void* __restrict__ bta, size_t wo,
    const int* __restrict__ pf, float* __restrict__ res, u16* __restrict__ xnb)
{
  const int isbf = *pf;
  int r = blockIdx.x;
  int tid = threadIdx.x;
  int b = r >> 11, s = r & 2047;
  int sr = rev ? (b * S_LEN + (S_LEN - 1 - s)) : r;
  float v;
  if (src_is_ext) v = ldw(src, (size_t)sr * DMODEL + tid, isbf);
  else            v = ((const float*)src)[(size_t)sr * DMODEL + tid];
  res[(size_t)r * DMODEL + tid] = v;
  float s1 = v, s2 = v * v;
#pragma unroll
  for (int o = 32; o > 0; o >>= 1) {
    s1 += __shfl_xor(s1, o, 64);
    s2 += __shfl_xor(s2, o, 64);
  }
  __shared__ float r1[4], r2[4];
  if ((tid & 63) == 0) { r1[tid >> 6] = s1; r2[tid >> 6] = s2; }
  __syncthreads();
  s1 = r1[0] + r1[1] + r1[2] + r1[3];
  s2 = r2[0] + r2[1] + r2[2] + r2[3];
  float mean = s1 * (1.f / DMODEL);
  float var  = s2 * (1.f / DMODEL) - mean * mean;
  float inv  = rsqrtf(var + 1e-5f);
  xnb[(size_t)r * DMODEL + tid] =
      f2bf((v - mean) * inv * ldw(g, wo + tid, isbf) + ldw(bta, wo + tid, isbf));
}

// ---------------- MFMA GEMM: C[M,N] = A(bf16 row-major) @ Wp(packed) [+res] ----------
// BM=128, BK=32, 256 thr = 4 waves. BN=128: waves 2x2 (64x64 each). BN=64: 4x1.
// OUTMODE 0: f32. 1: final dtype per flag. 2: bf16.
// OUTMODE 3: bf16 into cat buffer (row stride 512), optional row reversal + col offset.
template<int BN, int OUTMODE>
__global__ __launch_bounds__(256) void mfma_gemm(
    const u16* __restrict__ A, const u16* __restrict__ Wp, size_t wo,
    const float* __restrict__ res, void* __restrict__ Out,
    const int* __restrict__ pf, int N, int K, int rev, int coff)
{
  const int isbf = *pf;
  __shared__ __align__(16) u16 Asb[128 * 32];
  __shared__ __align__(16) u16 Bsb[BN * 32];
  int tid = threadIdx.x;
  int n0 = blockIdx.x * BN, m0 = blockIdx.y * 128;
  int w = tid >> 6, lane = tid & 63;
  int q = lane >> 4, r = lane & 15;
  constexpr int WM = (BN == 128) ? 4 : 2;
  const int wm0 = (BN == 128) ? ((w >> 1) * 4) : (w * 2);
  const int wn0 = (BN == 128) ? ((w & 1) * 4) : 0;
  f32x4 acc[WM][4];
#pragma unroll
  for (int i = 0; i < WM; ++i)
#pragma unroll
    for (int j = 0; j < 4; ++j) acc[i][j] = (f32x4){0.f, 0.f, 0.f, 0.f};

  const int kbs = K >> 5;
  int sm = tid >> 1, sq = (tid & 1) * 2;
  const u16* arow = A + (size_t)(m0 + sm) * K + sq * 8;
  u16* adst0 = Asb + ((sm >> 4) * 4 + sq) * 128 + (sm & 15) * 8;
  u16* adst1 = Asb + ((sm >> 4) * 4 + sq + 1) * 128 + (sm & 15) * 8;

  for (int k0 = 0; k0 < K; k0 += 32) {
    u16x8 a0 = *(const u16x8*)(arow + k0);
    u16x8 a1 = *(const u16x8*)(arow + k0 + 8);
    *(u16x8*)adst0 = a0;
    *(u16x8*)adst1 = a1;
#pragma unroll
    for (int p = tid; p < BN * 4; p += 256) {
      int nb = p >> 6, inner = (p & 63) * 8;
      const u16* srcb = Wp + wo + ((size_t)((n0 >> 4) + nb) * kbs + (k0 >> 5)) * 512 + inner;
      *(u16x8*)(Bsb + nb * 512 + inner) = *(const u16x8*)srcb;
    }
    __syncthreads();
    bf16x8 af[WM], bfr[4];
#pragma unroll
    for (int i = 0; i < WM; ++i)
      af[i] = *(const bf16x8*)(Asb + ((wm0 + i) * 4 + q) * 128 + r * 8);
#pragma unroll
    for (int j = 0; j < 4; ++j)
      bfr[j] = *(const bf16x8*)(Bsb + ((wn0 + j) * 4 + q) * 128 + r * 8);
#pragma unroll
    for (int i = 0; i < WM; ++i)
#pragma unroll
      for (int j = 0; j < 4; ++j)
        acc[i][j] = __builtin_amdgcn_mfma_f32_16x16x32_bf16(af[i], bfr[j], acc[i][j], 0, 0, 0);
    __syncthreads();
  }
#pragma unroll
  for (int i = 0; i < WM; ++i) {
    int rowb = m0 + (wm0 + i) * 16 + q * 4;
#pragma unroll
    for (int j = 0; j < 4; ++j) {
      int col = n0 + (wn0 + j) * 16 + r;
#pragma unroll
      for (int t = 0; t < 4; ++t) {
        int row = rowb + t;
        float v = acc[i][j][t];
        size_t lidx = (size_t)row * N + col;
        if (res) v += res[lidx];
        if (OUTMODE == 0)      ((float*)Out)[lidx] = v;
        else if (OUTMODE == 2) ((u16*)Out)[lidx] = f2bf(v);
        else if (OUTMODE == 3) {
          int bb = row >> 11, ss = row & 2047;
          int orow = rev ? (bb * S_LEN + (S_LEN - 1 - ss)) : row;
          ((u16*)Out)[(size_t)orow * 512 + col + coff] = f2bf(v);
        } else {
          if (isbf) ((u16*)Out)[lidx] = f2bf(v); else ((float*)Out)[lidx] = v;
        }
      }
    }
  }
}

// ---------------- causal depthwise conv K=4 + bias + SiLU (bf16 in/out) -------------
__global__ __launch_bounds__(256) void conv_kernel(
    const u16* __restrict__ xzb, const void* __restrict__ cw, const void* __restrict__ cb,
    size_t ow, size_t ob, const int* __restrict__ pf, u16* __restrict__ xcb)
{
  const int isbf = *pf;
  int idx = blockIdx.x * 256 + threadIdx.x;  // 4096*512
  int r = idx >> 9, d = idx & 511;
  int b = r >> 11, s = r & 2047;
  float acc = ldw(cb, ob + d, isbf);
#pragma unroll
  for (int k = 0; k < 4; ++k) {
    int t = s - 3 + k;
    if (t >= 0)
      acc += ldw(cw, ow + (size_t)d * 4 + k, isbf) * bf2f(xzb[((size_t)(b * S_LEN + t) << 10) + d]);
  }
  xcb[idx] = f2bf(siluf(acc));
}

// Phase 1: per-chunk scan aggregates, with delta computed in-kernel.
__global__ __launch_bounds__(256) void scan_chunk_kernel(
    const u16* __restrict__ xcb, const float* __restrict__ dBC,
    const void* __restrict__ A_log, size_t oA,
    const void* __restrict__ dtpw, size_t owt, const void* __restrict__ dtpb, size_t obt,
    const int* __restrict__ pf, float* __restrict__ aggA, float* __restrict__ aggB)
{
  const int isbf = *pf;
  __shared__ float sall[32][65];   // dBC rows: [0:32)=dt-proj, [32:48)=B, [48:64)=C
  __shared__ float sw[32][17];     // dtp_w[j][d0+e]
  __shared__ float sd[32][17];     // delta
  __shared__ float sx[32][17];     // xc
  __shared__ float sbias[16];
  int tid = threadIdx.x;
  int n = tid & 15, dl = tid >> 4;
  int d0 = blockIdx.x << 4;
  int c = blockIdx.y, b = blockIdx.z;
  int row0 = b * S_LEN + c * CLEN;
  for (int l = tid; l < 2048; l += 256) {
    int tl = l >> 6, e = l & 63;
    sall[tl][e] = dBC[(size_t)(row0 + tl) * 64 + e];
  }
  for (int l = tid; l < 512; l += 256) {
    int j = l >> 4, e = l & 15;
    sw[j][e] = ldw(dtpw, owt + (size_t)j * 512 + d0 + e, isbf);
    int tl = j;
    sx[tl][e] = bf2f(xcb[(size_t)(row0 + tl) * DINNER + d0 + e]);
  }
  if (tid < 16) sbias[tid] = ldw(dtpb, obt + d0 + tid, isbf);
  __syncthreads();
  for (int l = tid; l < 512; l += 256) {
    int tl = l >> 4, e = l & 15;
    float a = sbias[e];
#pragma unroll 8
    for (int j = 0; j < 32; ++j) a += sall[tl][j] * sw[j][e];
    sd[tl][e] = softplusf(a);
  }
  __syncthreads();
  float Ac = -__expf(ldw(A_log, oA + (size_t)(d0 + dl) * 16 + n, isbf));
  float h = 0.f, lacc = 0.f;
#pragma unroll 4
  for (int tt = 0; tt < CLEN; ++tt) {
    float de = sd[tt][dl];
    float xv = sx[tt][dl];
    float bv = sall[tt][32 + n];
    float u = de * Ac;
    h = __expf(u) * h + de * xv * bv;
    lacc += u;
  }
  size_t o = (((size_t)(b * NCHUNK + c) * DINNER) + d0 + dl) * 16 + n;
  aggA[o] = __expf(lacc);
  aggB[o] = h;
}

// Phase 2: exclusive prefix over chunks in place (aggB -> hpref).
__global__ __launch_bounds__(256) void scan_prefix_kernel(
    const float* __restrict__ aggA, float* __restrict__ aggB)
{
  int idx = blockIdx.x * 256 + threadIdx.x;
  int n = idx & 15, d = (idx >> 4) & 511, b = idx >> 13;
  float h = 0.f;
  for (int c = 0; c < NCHUNK; ++c) {
    size_t o = (((size_t)(b * NCHUNK + c) * DINNER) + d) * 16 + n;
    float a = aggA[o], t = aggB[o];
    aggB[o] = h;
    h = a * h + t;
  }
}

// Phase 3: replay with true init; delta in-kernel; gated bf16 out for out-proj A.
__global__ __launch_bounds__(256) void scan_apply_kernel(
    const u16* __restrict__ xcb, const float* __restrict__ dBC,
    const u16* __restrict__ xzb, const float* __restrict__ hpref,
    const void* __restrict__ A_log, size_t oA, const void* __restrict__ Dp, size_t oD,
    const void* __restrict__ dtpw, size_t owt, const void* __restrict__ dtpb, size_t obt,
    const int* __restrict__ pf, u16* __restrict__ ymb)
{
  const int isbf = *pf;
  __shared__ float sall[32][65];
  __shared__ float sw[32][17];
  __shared__ float sd[32][17];
  __shared__ float sx[32][17];
  __shared__ float sz[32][17];
  __shared__ float sy[32][17];
  __shared__ float sbias[16];
  int tid = threadIdx.x;
  int n = tid & 15, dl = tid >> 4;
  int d0 = blockIdx.x << 4;
  int c = blockIdx.y, b = blockIdx.z;
  int row0 = b * S_LEN + c * CLEN;
  for (int l = tid; l < 2048; l += 256) {
    int tl = l >> 6, e = l & 63;
    sall[tl][e] = dBC[(size_t)(row0 + tl) * 64 + e];
  }
  for (int l = tid; l < 512; l += 256) {
    int j = l >> 4, e = l & 15;
    sw[j][e] = ldw(dtpw, owt + (size_t)j * 512 + d0 + e, isbf);
    size_t rr = (size_t)(row0 + j);
    sx[j][e] = bf2f(xcb[rr * DINNER + d0 + e]);
    sz[j][e] = bf2f(xzb[(rr << 10) + 512 + d0 + e]);
  }
  if (tid < 16) sbias[tid] = ldw(dtpb, obt + d0 + tid, isbf);
  __syncthreads();
  for (int l = tid; l < 512; l += 256) {
    int tl = l >> 4, e = l & 15;
    float a = sbias[e];
#pragma unroll 8
    for (int j = 0; j < 32; ++j) a += sall[tl][j] * sw[j][e];
    sd[tl][e] = softplusf(a);
  }
  __syncthreads();
  float Ac = -__expf(ldw(A_log, oA + (size_t)(d0 + dl) * 16 + n, isbf));
  size_t o = (((size_t)(b * NCHUNK + c) * DINNER) + d0 + dl) * 16 + n;
  float h = hpref[o];
  float Dv = ldw(Dp, oD + d0 + dl, isbf);
#pragma unroll 4
  for (int tt = 0; tt < CLEN; ++tt) {
    float de = sd[tt][dl];
    float xv = sx[tt][dl];
    float bv = sall[tt][32 + n];
    float cv = sall[tt][48 + n];
    h = __expf(de * Ac) * h + de * xv * bv;
    float yc = h * cv;
    yc += __shfl_xor(yc, 1, 64);
    yc += __shfl_xor(yc, 2, 64);
    yc += __shfl_xor(yc, 4, 64);
    yc += __shfl_xor(yc, 8, 64);
    if (n == 0) sy[tt][dl] = yc + Dv * xv;
  }
  __syncthreads();
  for (int l = tid; l < 512; l += 256) {
    int tl = l >> 4, e = l & 15;
    ymb[(size_t)(row0 + tl) * DINNER + d0 + e] = f2bf(sy[tl][e] * siluf(sz[tl][e]));
  }
}

extern "C" void kernel_launch(void* const* d_in, const int* in_sizes, int n_in,
                              void* d_out, int out_size, void* d_ws, size_t ws_size,
                              hipStream_t stream)
{
  const void* x       = d_in[0];
  const void* in_w    = d_in[1];
  const void* conv_w  = d_in[2];
  const void* conv_b  = d_in[3];
  const void* A_log   = d_in[4];
  const void* xd_w    = d_in[5];
  const void* xB_w    = d_in[6];
  const void* xC_w    = d_in[7];
  const void* dtp_w   = d_in[8];
  const void* dtp_b   = d_in[9];
  const void* Dp      = d_in[10];
  const void* out_w   = d_in[11];
  const void* ln_g    = d_in[12];
  const void* ln_b    = d_in[13];
  const void* merge_w = d_in[14];

  const size_t M = 4096;
  // ---- workspace (~38.5 MB; proven-safe >= 50.5 MB) ----
  float* ws    = (float*)d_ws;
  float* res   = ws;                                        // 1.00 M floats
  float* dBC   = res + M * 256;                             // 0.25 M
  float* aggA  = dBC + M * 64;                              // 1.00 M (ym_bf alias)
  float* aggB  = aggA + (size_t)2 * NCHUNK * DINNER * 16;   // 1.00 M (-> hpref)
  float* obA   = aggB + (size_t)2 * NCHUNK * DINNER * 16;   // 1.00 M (blocks 0,2)
  u16*   xn_bf = (u16*)(obA + M * 256);                     // 1 M u16
  u16*   xz_bf = xn_bf + M * 256;                           // 4 M u16
  u16*   xc_bf = xz_bf + M * 1024;                          // 2 M u16
  u16*   cat_bf= xc_bf + M * 512;                           // 2 M u16
  u16*   Wp_in = cat_bf + M * 512;                          // 1 M u16
  u16*   Wp_out= Wp_in + (size_t)4 * 256 * 1024;            // 0.5 M u16
  u16*   Wp_mg = Wp_out + (size_t)4 * 512 * 256;            // 128 K u16
  u16*   Wp_all= Wp_mg + (size_t)512 * 256;                 // 128 K u16
  int*   flagp = (int*)(Wp_all + (size_t)4 * 512 * 64);
  u16*   ym_bf = (u16*)aggA;     // alias: aggA dead after scan_prefix

  dim3 blk(256);
  hipLaunchKernelGGL(detect_kernel, dim3(1), blk, 0, stream, x, flagp);
  hipLaunchKernelGGL(wpack_kernel, dim3(16, 8, 4), blk, 0, stream, in_w, flagp, Wp_in, 256, 1024);
  hipLaunchKernelGGL(wpack_kernel, dim3(4, 16, 4), blk, 0, stream, out_w, flagp, Wp_out, 512, 256);
  hipLaunchKernelGGL(wpack_kernel, dim3(4, 16, 1), blk, 0, stream, merge_w, flagp, Wp_mg, 512, 256);
  hipLaunchKernelGGL(wpack_fused_kernel, dim3(1, 16, 4), blk, 0, stream,
      xd_w, xB_w, xC_w, flagp, Wp_all);

  for (int i = 0; i < 4; ++i) {
    const void* src; int ext, rev;
    if (i == 0)      { src = x;   ext = 1; rev = 0; }
    else if (i == 1) { src = obA; ext = 0; rev = 0; }
    else if (i == 2) { src = x;   ext = 1; rev = 1; }
    else             { src = obA; ext = 0; rev = 0; }

    hipLaunchKernelGGL(ln_kernel, dim3(4096), blk, 0, stream,
        src, ext, rev, ln_g, ln_b, (size_t)i * 256, flagp, res, xn_bf);
    hipLaunchKernelGGL((mfma_gemm<128, 2>), dim3(8, 32), blk, 0, stream,
        xn_bf, Wp_in, (size_t)i * 256 * 1024, (const float*)nullptr, (void*)xz_bf,
        flagp, 1024, 256, 0, 0);
    hipLaunchKernelGGL(conv_kernel, dim3(8192), blk, 0, stream,
        xz_bf, conv_w, conv_b, (size_t)i * 512 * 4, (size_t)i * 512, flagp, xc_bf);
    hipLaunchKernelGGL((mfma_gemm<64, 0>), dim3(1, 32), blk, 0, stream,
        xc_bf, Wp_all, (size_t)i * 512 * 64, (const float*)nullptr, (void*)dBC,
        flagp, 64, 512, 0, 0);
    hipLaunchKernelGGL(scan_chunk_kernel, dim3(32, 64, 2), blk, 0, stream,
        xc_bf, dBC, A_log, (size_t)i * 512 * 16,
        dtp_w, (size_t)i * 32 * 512, dtp_b, (size_t)i * 512,
        flagp, aggA, aggB);
    hipLaunchKernelGGL(scan_prefix_kernel, dim3(64), blk, 0, stream, aggA, aggB);
    hipLaunchKernelGGL(scan_apply_kernel, dim3(32, 64, 2), blk, 0, stream,
        xc_bf, dBC, xz_bf, aggB, A_log, (size_t)i * 512 * 16, Dp, (size_t)i * 512,
        dtp_w, (size_t)i * 32 * 512, dtp_b, (size_t)i * 512,
        flagp, ym_bf);
    if (i == 0 || i == 2) {
      hipLaunchKernelGGL((mfma_gemm<128, 0>), dim3(2, 32), blk, 0, stream,
          ym_bf, Wp_out, (size_t)i * 512 * 256, res, (void*)obA, flagp, 256, 512, 0, 0);
    } else {
      hipLaunchKernelGGL((mfma_gemm<128, 3>), dim3(2, 32), blk, 0, stream,
          ym_bf, Wp_out, (size_t)i * 512 * 256, res, (void*)cat_bf, flagp, 256, 512,
          (i == 3) ? 1 : 0, (i == 1) ? 0 : 256);
    }
  }
  hipLaunchKernelGGL((mfma_gemm<128, 1>), dim3(2, 32), blk, 0, stream,
      cat_bf, Wp_mg, (size_t)0, (const float*)nullptr, d_out, flagp, 256, 512, 0, 0);
}